// Round 3
// baseline (210.991 us; speedup 1.0000x reference)
//
#include <hip/hip_runtime.h>

typedef __bf16 bf16;
typedef __attribute__((ext_vector_type(8))) __bf16 bf16x8;
typedef __attribute__((ext_vector_type(4))) float f32x4;

#define LOG2E 1.44269504088896f
#define SCALE 0.125f   // 1/sqrt(64)

__device__ inline f32x4 mfma16(bf16x8 a, bf16x8 b, f32x4 c) {
    return __builtin_amdgcn_mfma_f32_16x16x32_bf16(a, b, c, 0, 0, 0);
}

// ---------------------------------------------------------------- prep ------
__global__ __launch_bounds__(256) void prep_kernel(
        const float* __restrict__ h, const float* __restrict__ x,
        const float* __restrict__ Wq, const float* __restrict__ Wk,
        const float* __restrict__ Wv, const float* __restrict__ Wo,
        const float* __restrict__ bq, const float* __restrict__ bk,
        const float* __restrict__ bv,
        bf16* __restrict__ hb, bf16* __restrict__ wpack, bf16* __restrict__ wob,
        float* __restrict__ bqkv, bf16* __restrict__ xb, float* __restrict__ sqx) {
    int stride = gridDim.x * blockDim.x;
    int tid = blockIdx.x * blockDim.x + threadIdx.x;
    for (int i = tid; i < 4096 * 512; i += stride) hb[i] = (bf16)h[i];
    for (int i = tid; i < 3 * 512 * 512; i += stride) {
        float v = (i < 262144) ? Wq[i] : (i < 524288 ? Wk[i - 262144] : Wv[i - 524288]);
        wpack[i] = (bf16)v;
    }
    for (int i = tid; i < 512 * 512; i += stride) wob[i] = (bf16)Wo[i];
    for (int i = tid; i < 1536; i += stride)
        bqkv[i] = (i < 512) ? bq[i] : (i < 1024 ? bk[i - 512] : bv[i - 1024]);
    for (int i = tid; i < 4096 * 48; i += stride) xb[i] = (bf16)x[i];
    for (int i = tid; i < 4096 * 3; i += stride) {
        int row = i / 3, c = i - row * 3;
        float s = 0.0f;
        for (int k = 0; k < 16; k++) {
            float v = (float)(bf16)x[row * 48 + c * 16 + k];
            s += v * v;
        }
        sqx[i] = s;
    }
}

// ---------------------------------------------------------- QKV GEMM --------
// out[n][m] = sum_k hb[n][k] * wpack[m][k] + bias[m]
// Q,K scattered to (B,H,N,64); V scattered TRANSPOSED to (B,H,64,N)
__global__ __launch_bounds__(256) void gemm_qkv_kernel(
        const bf16* __restrict__ A, const bf16* __restrict__ Bm,
        const float* __restrict__ bias,
        bf16* __restrict__ Qb, bf16* __restrict__ Kb, bf16* __restrict__ Vt) {
    __shared__ bf16 Al[64][72];
    __shared__ bf16 Bl[64][72];
    int t = threadIdx.x;
    int w = t >> 6, lane = t & 63, g = lane >> 4, lo = lane & 15;
    int rowbase = blockIdx.x * 64, colbase = blockIdx.y * 64;
    int wr = (w >> 1) * 32, wc = (w & 1) * 32;
    f32x4 acc[2][2] = {};
    int sr = t >> 2, sc = (t & 3) * 16;
    for (int kb = 0; kb < 512; kb += 64) {
        *(bf16x8*)&Al[sr][sc]     = *(const bf16x8*)&A[(rowbase + sr) * 512 + kb + sc];
        *(bf16x8*)&Al[sr][sc + 8] = *(const bf16x8*)&A[(rowbase + sr) * 512 + kb + sc + 8];
        *(bf16x8*)&Bl[sr][sc]     = *(const bf16x8*)&Bm[(colbase + sr) * 512 + kb + sc];
        *(bf16x8*)&Bl[sr][sc + 8] = *(const bf16x8*)&Bm[(colbase + sr) * 512 + kb + sc + 8];
        __syncthreads();
        for (int kk = 0; kk < 64; kk += 32) {
            bf16x8 af[2], bfr[2];
            af[0]  = *(const bf16x8*)&Al[wr + lo][kk + 8 * g];
            af[1]  = *(const bf16x8*)&Al[wr + 16 + lo][kk + 8 * g];
            bfr[0] = *(const bf16x8*)&Bl[wc + lo][kk + 8 * g];
            bfr[1] = *(const bf16x8*)&Bl[wc + 16 + lo][kk + 8 * g];
            for (int ri = 0; ri < 2; ri++)
                for (int ci = 0; ci < 2; ci++)
                    acc[ri][ci] = mfma16(af[ri], bfr[ci], acc[ri][ci]);
        }
        __syncthreads();
    }
    for (int ri = 0; ri < 2; ri++)
        for (int ci = 0; ci < 2; ci++) {
            int mcol = colbase + wc + 16 * ci + lo;
            float bv = bias[mcol];
            int proj = mcol >> 9, hm = mcol & 511, head = hm >> 6, d = hm & 63;
            for (int r = 0; r < 4; r++) {
                int n = rowbase + wr + 16 * ri + 4 * g + r;
                int bidx = n >> 10, i = n & 1023;
                bf16 val = (bf16)(acc[ri][ci][r] + bv);
                if (proj == 0)
                    Qb[((size_t)(bidx * 8 + head) * 1024 + i) * 64 + d] = val;
                else if (proj == 1)
                    Kb[((size_t)(bidx * 8 + head) * 1024 + i) * 64 + d] = val;
                else
                    Vt[((size_t)(bidx * 8 + head) * 64 + d) * 1024 + i] = val;
            }
        }
}

// ----------------------------------------------------- fused attention ------
// KV-split flash attention: each block handles 64 query rows x (1024/nsplit) keys,
// writes unnormalized partial O + per-row (m,l). merge_kernel combines splits.
__global__ __launch_bounds__(256) void attn_kernel(
        const bf16* __restrict__ Qb, const bf16* __restrict__ Kb,
        const bf16* __restrict__ Vt, const bf16* __restrict__ xb,
        const float* __restrict__ sqx, const float* __restrict__ alpha,
        const float* __restrict__ log_sigma, int nsplit,
        float* __restrict__ o_part, float* __restrict__ ml_part) {
    __shared__ bf16 Klds[64][72];
    __shared__ bf16 Xlds[64][56];
    __shared__ bf16 VTlds[64][72];
    __shared__ float sqj[3][64];
    __shared__ bf16 Plds[4][16][72];

    int t = threadIdx.x;
    int w = t >> 6, lane = t & 63, g = lane >> 4, lo = lane & 15;
    int zz = blockIdx.z;
    int b = zz / nsplit, split = zz - b * nsplit;
    int hh = blockIdx.y;
    int i0 = blockIdx.x * 64 + w * 16;   // this wave's 16 query rows

    float alf[3], coef[3];
    for (int c = 0; c < 3; c++) {
        alf[c] = alpha[hh * 3 + c];
        float sg = expf(log_sigma[hh * 3 + c]);
        sg = fmaxf(sg, 1e-4f);
        coef[c] = -LOG2E / (2.0f * sg * sg);
    }

    // Q fragments (rows = lane&15, k-enum 8g+e, consistent with K frags)
    const bf16* Qbase = Qb + ((size_t)(b * 8 + hh) * 1024 + i0) * 64;
    bf16x8 qa[2];
    qa[0] = *(const bf16x8*)&Qbase[lo * 64 + 8 * g];
    qa[1] = *(const bf16x8*)&Qbase[lo * 64 + 32 + 8 * g];

    // Xq fragments (K padded 16->32: lanes g>=2 hold zeros)
    bf16x8 xqa[3];
    const bf16* Xibase = xb + ((size_t)(b << 10) + i0) * 48;
    for (int c = 0; c < 3; c++) {
        bf16x8 v = {};
        if (g < 2) v = *(const bf16x8*)&Xibase[lo * 48 + c * 16 + 8 * g];
        xqa[c] = v;
    }

    // per-row |x|^2 for this wave's rows (row = 4g + r)
    float sqi[3][4];
    const float* sqibase = sqx + ((size_t)(b << 10) + i0) * 3;
    for (int r = 0; r < 4; r++)
        for (int c = 0; c < 3; c++) sqi[c][r] = sqibase[(4 * g + r) * 3 + c];

    float m_r[4], l_r[4];
    f32x4 o[4];
    for (int r = 0; r < 4; r++) { m_r[r] = -1e30f; l_r[r] = 0.0f; }
    for (int td = 0; td < 4; td++) o[td] = (f32x4){0.f, 0.f, 0.f, 0.f};

    int sr = t >> 2, sc = (t & 3) * 16;
    int jlen = 1024 / nsplit, jb = split * jlen;
    for (int j0 = jb; j0 < jb + jlen; j0 += 64) {
        __syncthreads();   // previous tile's reads complete before overwrite
        const bf16* Kbase = Kb + ((size_t)(b * 8 + hh) * 1024 + j0) * 64;
        *(bf16x8*)&Klds[sr][sc]     = *(const bf16x8*)&Kbase[sr * 64 + sc];
        *(bf16x8*)&Klds[sr][sc + 8] = *(const bf16x8*)&Kbase[sr * 64 + sc + 8];
        // V^T tile: rows d, cols j -- direct vector loads from pre-transposed Vt
        const bf16* Vbase = Vt + ((size_t)(b * 8 + hh) * 64) * 1024 + j0;
        *(bf16x8*)&VTlds[sr][sc]     = *(const bf16x8*)&Vbase[sr * 1024 + sc];
        *(bf16x8*)&VTlds[sr][sc + 8] = *(const bf16x8*)&Vbase[sr * 1024 + sc + 8];
        for (int idx = t; idx < 384; idx += 256) {
            int xr = idx / 6, xc = (idx - xr * 6) * 8;
            *(bf16x8*)&Xlds[xr][xc] = *(const bf16x8*)&xb[((size_t)(b << 10) + j0 + xr) * 48 + xc];
        }
        if (t < 192) {
            int jl = t / 3, c = t - jl * 3;
            sqj[c][jl] = sqx[((size_t)(b << 10) + j0 + jl) * 3 + c];
        }
        __syncthreads();

        // S tiles: QK^T * scale + geodesic bias
        f32x4 s[4];
        for (int tt = 0; tt < 4; tt++) {
            f32x4 acc = {};
            bf16x8 kb0 = *(const bf16x8*)&Klds[16 * tt + lo][8 * g];
            bf16x8 kb1 = *(const bf16x8*)&Klds[16 * tt + lo][32 + 8 * g];
            acc = mfma16(qa[0], kb0, acc);
            acc = mfma16(qa[1], kb1, acc);
            f32x4 ic[3];
            for (int c = 0; c < 3; c++) {
                bf16x8 xbf = {};
                if (g < 2) xbf = *(const bf16x8*)&Xlds[16 * tt + lo][c * 16 + 8 * g];
                f32x4 z = {};
                ic[c] = mfma16(xqa[c], xbf, z);
            }
            for (int r = 0; r < 4; r++) {
                float sv = acc[r] * SCALE;
                for (int c = 0; c < 3; c++) {
                    float d = sqi[c][r] + sqj[c][16 * tt + lo] - 2.0f * ic[c][r];
                    d = fmaxf(d, 0.0f);
                    sv += alf[c] * exp2f(coef[c] * d);
                }
                acc[r] = sv;
            }
            s[tt] = acc;
        }

        // online softmax (rows live on 16-lane groups: row = 4g + r)
        float pm[4], sf[4], rs[4];
        for (int r = 0; r < 4; r++)
            pm[r] = fmaxf(fmaxf(s[0][r], s[1][r]), fmaxf(s[2][r], s[3][r]));
        for (int msk = 1; msk < 16; msk <<= 1)
            for (int r = 0; r < 4; r++) pm[r] = fmaxf(pm[r], __shfl_xor(pm[r], msk));
        for (int r = 0; r < 4; r++) {
            float mn = fmaxf(m_r[r], pm[r]);
            sf[r] = exp2f((m_r[r] - mn) * LOG2E);
            m_r[r] = mn;
            rs[r] = 0.0f;
        }
        for (int tt = 0; tt < 4; tt++)
            for (int r = 0; r < 4; r++) {
                float p = exp2f((s[tt][r] - m_r[r]) * LOG2E);
                s[tt][r] = p;
                rs[r] += p;
            }
        for (int msk = 1; msk < 16; msk <<= 1)
            for (int r = 0; r < 4; r++) rs[r] += __shfl_xor(rs[r], msk);
        for (int r = 0; r < 4; r++) l_r[r] = l_r[r] * sf[r] + rs[r];

        // P -> LDS (bf16), per-wave private buffer
        for (int tt = 0; tt < 4; tt++)
            for (int r = 0; r < 4; r++)
                Plds[w][4 * g + r][16 * tt + lo] = (bf16)s[tt][r];

        for (int td = 0; td < 4; td++)
            for (int r = 0; r < 4; r++) o[td][r] *= sf[r];

        // PV: A = P (rows=lane&15), B = V^T (cols d = lane&15)
        bf16x8 pa0 = *(const bf16x8*)&Plds[w][lo][8 * g];
        bf16x8 pa1 = *(const bf16x8*)&Plds[w][lo][32 + 8 * g];
        for (int td = 0; td < 4; td++) {
            bf16x8 vb0 = *(const bf16x8*)&VTlds[16 * td + lo][8 * g];
            bf16x8 vb1 = *(const bf16x8*)&VTlds[16 * td + lo][32 + 8 * g];
            o[td] = mfma16(pa0, vb0, o[td]);
            o[td] = mfma16(pa1, vb1, o[td]);
        }
    }

    // write unnormalized partials
    for (int td = 0; td < 4; td++)
        for (int r = 0; r < 4; r++) {
            int i = i0 + 4 * g + r;
            size_t rowg = (size_t)(b * 8 + hh) * 1024 + i;
            o_part[((size_t)split * 32768 + rowg) * 64 + 16 * td + lo] = o[td][r];
        }
    if (lo == 0)
        for (int r = 0; r < 4; r++) {
            int i = i0 + 4 * g + r;
            size_t rowg = (size_t)(b * 8 + hh) * 1024 + i;
            ml_part[((size_t)split * 32768 + rowg) * 2]     = m_r[r];
            ml_part[((size_t)split * 32768 + rowg) * 2 + 1] = l_r[r];
        }
}

// -------------------------------------------------------------- merge -------
__global__ __launch_bounds__(256) void merge_kernel(
        const float* __restrict__ o_part, const float* __restrict__ ml_part,
        int nsplit, bf16* __restrict__ attnout) {
    int t = threadIdx.x;
    int rowg = blockIdx.x * 16 + (t >> 4);
    int d4 = (t & 15) * 4;
    float m0 = ml_part[(size_t)rowg * 2], l0 = ml_part[(size_t)rowg * 2 + 1];
    float m1 = -1e30f, l1 = 0.0f;
    if (nsplit == 2) {
        m1 = ml_part[((size_t)32768 + rowg) * 2];
        l1 = ml_part[((size_t)32768 + rowg) * 2 + 1];
    }
    float M = fmaxf(m0, m1);
    float w0 = exp2f((m0 - M) * LOG2E);
    float w1 = exp2f((m1 - M) * LOG2E);
    float inv = 1.0f / (w0 * l0 + w1 * l1);
    f32x4 a = *(const f32x4*)&o_part[(size_t)rowg * 64 + d4];
    f32x4 bv = (f32x4){0.f, 0.f, 0.f, 0.f};
    if (nsplit == 2) bv = *(const f32x4*)&o_part[((size_t)32768 + rowg) * 64 + d4];
    int b = rowg >> 13, hh = (rowg >> 10) & 7, i = rowg & 1023;
    bf16* dst = &attnout[((size_t)(b << 10) + i) * 512 + hh * 64 + d4];
    for (int q = 0; q < 4; q++)
        dst[q] = (bf16)((w0 * a[q] + w1 * bv[q]) * inv);
}

// ----------------------------------------------------- output GEMM ----------
__global__ __launch_bounds__(256) void gemm_out_kernel(
        const bf16* __restrict__ A, const bf16* __restrict__ Bm,
        const float* __restrict__ bias, float* __restrict__ out) {
    __shared__ bf16 Al[64][72];
    __shared__ bf16 Bl[64][72];
    int t = threadIdx.x;
    int w = t >> 6, lane = t & 63, g = lane >> 4, lo = lane & 15;
    int rowbase = blockIdx.x * 64, colbase = blockIdx.y * 64;
    int wr = (w >> 1) * 32, wc = (w & 1) * 32;
    f32x4 acc[2][2] = {};
    int sr = t >> 2, sc = (t & 3) * 16;
    for (int kb = 0; kb < 512; kb += 64) {
        *(bf16x8*)&Al[sr][sc]     = *(const bf16x8*)&A[(rowbase + sr) * 512 + kb + sc];
        *(bf16x8*)&Al[sr][sc + 8] = *(const bf16x8*)&A[(rowbase + sr) * 512 + kb + sc + 8];
        *(bf16x8*)&Bl[sr][sc]     = *(const bf16x8*)&Bm[(colbase + sr) * 512 + kb + sc];
        *(bf16x8*)&Bl[sr][sc + 8] = *(const bf16x8*)&Bm[(colbase + sr) * 512 + kb + sc + 8];
        __syncthreads();
        for (int kk = 0; kk < 64; kk += 32) {
            bf16x8 af[2], bfr[2];
            af[0]  = *(const bf16x8*)&Al[wr + lo][kk + 8 * g];
            af[1]  = *(const bf16x8*)&Al[wr + 16 + lo][kk + 8 * g];
            bfr[0] = *(const bf16x8*)&Bl[wc + lo][kk + 8 * g];
            bfr[1] = *(const bf16x8*)&Bl[wc + 16 + lo][kk + 8 * g];
            for (int ri = 0; ri < 2; ri++)
                for (int ci = 0; ci < 2; ci++)
                    acc[ri][ci] = mfma16(af[ri], bfr[ci], acc[ri][ci]);
        }
        __syncthreads();
    }
    for (int ri = 0; ri < 2; ri++)
        for (int ci = 0; ci < 2; ci++) {
            int mcol = colbase + wc + 16 * ci + lo;
            float bv = bias[mcol];
            for (int r = 0; r < 4; r++) {
                int n = rowbase + wr + 16 * ri + 4 * g + r;
                out[(size_t)n * 512 + mcol] = acc[ri][ci][r] + bv;
            }
        }
}

// ---------------------------------------------------------------- launch ----
extern "C" void kernel_launch(void* const* d_in, const int* in_sizes, int n_in,
                              void* d_out, int out_size, void* d_ws, size_t ws_size,
                              hipStream_t stream) {
    const float* h  = (const float*)d_in[0];
    const float* x  = (const float*)d_in[1];
    const float* Wq = (const float*)d_in[2];
    const float* bq = (const float*)d_in[3];
    const float* Wk = (const float*)d_in[4];
    const float* bk = (const float*)d_in[5];
    const float* Wv = (const float*)d_in[6];
    const float* bv = (const float*)d_in[7];
    const float* Wo = (const float*)d_in[8];
    const float* bo = (const float*)d_in[9];
    const float* alpha     = (const float*)d_in[10];
    const float* log_sigma = (const float*)d_in[11];
    float* out = (float*)d_out;

    char* ws = (char*)d_ws;
    size_t off = 0;
    auto alloc = [&](size_t bytes) {
        char* p = ws + off;
        off += (bytes + 255) & ~(size_t)255;
        return p;
    };
    bf16*  hb      = (bf16*)alloc(4096 * 512 * 2);
    bf16*  wpack   = (bf16*)alloc(1536 * 512 * 2);
    bf16*  wob     = (bf16*)alloc(512 * 512 * 2);
    float* bqkv    = (float*)alloc(1536 * 4);
    bf16*  xb      = (bf16*)alloc(4096 * 48 * 2);
    float* sqx     = (float*)alloc(4096 * 3 * 4);
    bf16*  Qb      = (bf16*)alloc((size_t)4 * 8 * 1024 * 64 * 2);
    bf16*  Kb      = (bf16*)alloc((size_t)4 * 8 * 1024 * 64 * 2);
    bf16*  Vt      = (bf16*)alloc((size_t)4 * 8 * 1024 * 64 * 2);
    bf16*  attnout = (bf16*)alloc(4096 * 512 * 2);
    size_t base = off;

    // KV-split partials: o (f32) + (m,l) per row per split
    size_t need2 = base + 2 * ((size_t)32768 * 64 * 4 + 1024) + 2 * ((size_t)32768 * 2 * 4 + 1024);
    int nsplit = (ws_size >= need2) ? 2 : 1;
    float* o_part  = (float*)alloc((size_t)nsplit * 32768 * 64 * 4);
    float* ml_part = (float*)alloc((size_t)nsplit * 32768 * 2 * 4);

    prep_kernel<<<512, 256, 0, stream>>>(h, x, Wq, Wk, Wv, Wo, bq, bk, bv,
                                         hb, wpack, wob, bqkv, xb, sqx);
    gemm_qkv_kernel<<<dim3(64, 24), 256, 0, stream>>>(hb, wpack, bqkv, Qb, Kb, Vt);
    attn_kernel<<<dim3(16, 8, 4 * nsplit), 256, 0, stream>>>(
        Qb, Kb, Vt, xb, sqx, alpha, log_sigma, nsplit, o_part, ml_part);
    merge_kernel<<<2048, 256, 0, stream>>>(o_part, ml_part, nsplit, attnout);
    gemm_out_kernel<<<dim3(64, 8), 256, 0, stream>>>(attnout, wob, bo, out);
}

// Round 4
// 200.759 us; speedup vs baseline: 1.0510x; 1.0510x over previous
//
#include <hip/hip_runtime.h>

typedef __bf16 bf16;
typedef __attribute__((ext_vector_type(8))) __bf16 bf16x8;
typedef __attribute__((ext_vector_type(4))) float f32x4;

#define LOG2E 1.44269504088896f
#define SCALE 0.125f   // 1/sqrt(64)

__device__ inline f32x4 mfma16(bf16x8 a, bf16x8 b, f32x4 c) {
    return __builtin_amdgcn_mfma_f32_16x16x32_bf16(a, b, c, 0, 0, 0);
}

// ---------------------------------------------------------------- prep ------
// Converts inputs to bf16, packs QKV weights, and precomputes the factorized
// geodesic terms: Aexp[i,h,c] = alpha[h,c]*2^(coef*|x_i,c|^2),
//                 Bexp[b,h,j,c] = 2^(coef*|x_j,c|^2),  coef = -log2e/(2 sigma^2)
__global__ __launch_bounds__(256) void prep_kernel(
        const float* __restrict__ h, const float* __restrict__ x,
        const float* __restrict__ Wq, const float* __restrict__ Wk,
        const float* __restrict__ Wv, const float* __restrict__ Wo,
        const float* __restrict__ bq, const float* __restrict__ bk,
        const float* __restrict__ bv, const float* __restrict__ alpha,
        const float* __restrict__ log_sigma,
        bf16* __restrict__ hb, bf16* __restrict__ wpack, bf16* __restrict__ wob,
        float* __restrict__ bqkv, bf16* __restrict__ xb,
        float* __restrict__ Aexp, float* __restrict__ Bexp) {
    int stride = gridDim.x * blockDim.x;
    int tid = blockIdx.x * blockDim.x + threadIdx.x;
    for (int i = tid; i < 4096 * 512; i += stride) hb[i] = (bf16)h[i];
    for (int i = tid; i < 3 * 512 * 512; i += stride) {
        float v = (i < 262144) ? Wq[i] : (i < 524288 ? Wk[i - 262144] : Wv[i - 524288]);
        wpack[i] = (bf16)v;
    }
    for (int i = tid; i < 512 * 512; i += stride) wob[i] = (bf16)Wo[i];
    for (int i = tid; i < 1536; i += stride)
        bqkv[i] = (i < 512) ? bq[i] : (i < 1024 ? bk[i - 512] : bv[i - 1024]);
    for (int i = tid; i < 4096 * 48; i += stride) xb[i] = (bf16)x[i];
    for (int i = tid; i < 4096 * 3; i += stride) {
        int row = i / 3, c = i - row * 3;
        float s = 0.0f;
        for (int k = 0; k < 16; k++) {
            float v = (float)(bf16)x[row * 48 + c * 16 + k];
            s += v * v;
        }
        int b = row >> 10, jj = row & 1023;
        for (int hh = 0; hh < 8; hh++) {
            float sg = fmaxf(expf(log_sigma[hh * 3 + c]), 1e-4f);
            float coef = -(0.5f * LOG2E) / (sg * sg);
            float e = exp2f(coef * s);
            Aexp[((size_t)row * 8 + hh) * 3 + c] = alpha[hh * 3 + c] * e;
            Bexp[(((size_t)(b * 8 + hh)) * 1024 + jj) * 3 + c] = e;
        }
    }
}

// ---------------------------------------------------------- QKV GEMM --------
// out[n][m] = sum_k hb[n][k] * wpack[m][k] + bias[m]
// Q,K -> (B,H,N,64); V -> TRANSPOSED (B,H,64,N). Epilogue goes through LDS so
// all global stores are coalesced bf16x8 (no scattered scalar stores).
__global__ __launch_bounds__(256) void gemm_qkv_kernel(
        const bf16* __restrict__ A, const bf16* __restrict__ Bm,
        const float* __restrict__ bias,
        bf16* __restrict__ Qb, bf16* __restrict__ Kb, bf16* __restrict__ Vt) {
    __shared__ bf16 Al[64][72];
    __shared__ bf16 Bl[64][72];
    int t = threadIdx.x;
    int w = t >> 6, lane = t & 63, g = lane >> 4, lo = lane & 15;
    int rowbase = blockIdx.x * 64, colbase = blockIdx.y * 64;
    int wr = (w >> 1) * 32, wc = (w & 1) * 32;
    f32x4 acc[2][2] = {};
    int sr = t >> 2, sc = (t & 3) * 16;
    for (int kb = 0; kb < 512; kb += 64) {
        *(bf16x8*)&Al[sr][sc]     = *(const bf16x8*)&A[(rowbase + sr) * 512 + kb + sc];
        *(bf16x8*)&Al[sr][sc + 8] = *(const bf16x8*)&A[(rowbase + sr) * 512 + kb + sc + 8];
        *(bf16x8*)&Bl[sr][sc]     = *(const bf16x8*)&Bm[(colbase + sr) * 512 + kb + sc];
        *(bf16x8*)&Bl[sr][sc + 8] = *(const bf16x8*)&Bm[(colbase + sr) * 512 + kb + sc + 8];
        __syncthreads();
        for (int kk = 0; kk < 64; kk += 32) {
            bf16x8 af[2], bfr[2];
            af[0]  = *(const bf16x8*)&Al[wr + lo][kk + 8 * g];
            af[1]  = *(const bf16x8*)&Al[wr + 16 + lo][kk + 8 * g];
            bfr[0] = *(const bf16x8*)&Bl[wc + lo][kk + 8 * g];
            bfr[1] = *(const bf16x8*)&Bl[wc + 16 + lo][kk + 8 * g];
            for (int ri = 0; ri < 2; ri++)
                for (int ci = 0; ci < 2; ci++)
                    acc[ri][ci] = mfma16(af[ri], bfr[ci], acc[ri][ci]);
        }
        __syncthreads();
    }
    // stage C tile (with bias) to LDS
    for (int ri = 0; ri < 2; ri++)
        for (int ci = 0; ci < 2; ci++) {
            int ccol = wc + 16 * ci + lo;
            float bv = bias[colbase + ccol];
            for (int r = 0; r < 4; r++)
                Al[wr + 16 * ri + 4 * g + r][ccol] = (bf16)(acc[ri][ci][r] + bv);
        }
    __syncthreads();
    // coalesced stores: colbase is 64-aligned -> exactly one (proj, head)
    int proj = colbase >> 9, head = (colbase >> 6) & 7;
    int bidx = rowbase >> 10, i0 = rowbase & 1023;
    int row = t >> 2, c16 = (t & 3) * 16;
    if (proj < 2) {
        bf16* dst = (proj == 0 ? Qb : Kb) +
                    ((size_t)(bidx * 8 + head) * 1024 + i0 + row) * 64 + c16;
        *(bf16x8*)dst       = *(const bf16x8*)&Al[row][c16];
        *(bf16x8*)(dst + 8) = *(const bf16x8*)&Al[row][c16 + 8];
    } else {
        bf16x8 v0, v1;
        for (int k = 0; k < 8; k++) v0[k] = Al[c16 + k][row];
        for (int k = 0; k < 8; k++) v1[k] = Al[c16 + 8 + k][row];
        bf16* dst = Vt + ((size_t)(bidx * 8 + head) * 64 + row) * 1024 + i0 + c16;
        *(bf16x8*)dst       = v0;
        *(bf16x8*)(dst + 8) = v1;
    }
}

// ----------------------------------------------------- fused attention ------
// KV-split flash attention with factorized geodesic bias:
// bias = sum_c Aexp[i,h,c] * Bexp[j,h,c] * 2^(k2_c * <x_i,x_j>_c)
__global__ __launch_bounds__(256) void attn_kernel(
        const bf16* __restrict__ Qb, const bf16* __restrict__ Kb,
        const bf16* __restrict__ Vt, const bf16* __restrict__ xb,
        const float* __restrict__ Aexp, const float* __restrict__ Bexp,
        const float* __restrict__ log_sigma, int nsplit,
        float* __restrict__ o_part, float* __restrict__ ml_part) {
    __shared__ bf16 Klds[64][72];
    __shared__ bf16 VTlds[64][72];
    __shared__ float Blds[3][64];
    __shared__ __align__(16) char PXbuf[9216];   // X tile [64][56] aliased with P [4][16][72]
    bf16 (*Xlds)[56] = (bf16 (*)[56])PXbuf;

    int t = threadIdx.x;
    int w = t >> 6, lane = t & 63, g = lane >> 4, lo = lane & 15;
    bf16* Pw = (bf16*)PXbuf + (size_t)w * 16 * 72;
    int zz = blockIdx.z;
    int b = zz / nsplit, split = zz - b * nsplit;
    int hh = blockIdx.y;
    int i0 = blockIdx.x * 64 + w * 16;   // this wave's 16 query rows

    float k2[3];
    for (int c = 0; c < 3; c++) {
        float sg = fmaxf(expf(log_sigma[hh * 3 + c]), 1e-4f);
        k2[c] = LOG2E / (sg * sg);       // = -2*coef
    }

    // Q fragments (rows = lane&15, k-enum 8g+e, consistent with K frags)
    const bf16* Qbase = Qb + ((size_t)(b * 8 + hh) * 1024 + i0) * 64;
    bf16x8 qa[2];
    qa[0] = *(const bf16x8*)&Qbase[lo * 64 + 8 * g];
    qa[1] = *(const bf16x8*)&Qbase[lo * 64 + 32 + 8 * g];

    // Xq fragments (K padded 16->32: lanes g>=2 hold zeros)
    bf16x8 xqa[3];
    const bf16* Xibase = xb + ((size_t)(b << 10) + i0) * 48;
    for (int c = 0; c < 3; c++) {
        bf16x8 v = {};
        if (g < 2) v = *(const bf16x8*)&Xibase[lo * 48 + c * 16 + 8 * g];
        xqa[c] = v;
    }

    // A-side factor for this wave's rows (row = 4g + r)
    float af[3][4];
    for (int r = 0; r < 4; r++)
        for (int c = 0; c < 3; c++)
            af[c][r] = Aexp[(((size_t)(b << 10) + i0 + 4 * g + r) * 8 + hh) * 3 + c];

    float m_r[4], l_r[4];
    f32x4 o[4];
    for (int r = 0; r < 4; r++) { m_r[r] = -1e30f; l_r[r] = 0.0f; }
    for (int td = 0; td < 4; td++) o[td] = (f32x4){0.f, 0.f, 0.f, 0.f};

    int sr = t >> 2, sc = (t & 3) * 16;
    int jlen = 1024 / nsplit, jb = split * jlen;
    for (int j0 = jb; j0 < jb + jlen; j0 += 64) {
        __syncthreads();   // previous tile's reads complete before overwrite
        const bf16* Kbase = Kb + ((size_t)(b * 8 + hh) * 1024 + j0) * 64;
        *(bf16x8*)&Klds[sr][sc]     = *(const bf16x8*)&Kbase[sr * 64 + sc];
        *(bf16x8*)&Klds[sr][sc + 8] = *(const bf16x8*)&Kbase[sr * 64 + sc + 8];
        const bf16* Vbase = Vt + ((size_t)(b * 8 + hh) * 64) * 1024 + j0;
        *(bf16x8*)&VTlds[sr][sc]     = *(const bf16x8*)&Vbase[sr * 1024 + sc];
        *(bf16x8*)&VTlds[sr][sc + 8] = *(const bf16x8*)&Vbase[sr * 1024 + sc + 8];
        for (int idx = t; idx < 384; idx += 256) {
            int xr = idx / 6, xc = (idx - xr * 6) * 8;
            *(bf16x8*)&Xlds[xr][xc] = *(const bf16x8*)&xb[((size_t)(b << 10) + j0 + xr) * 48 + xc];
        }
        if (t < 192) {
            int jl = t & 63, c = t >> 6;
            Blds[c][jl] = Bexp[(((size_t)(b * 8 + hh)) * 1024 + j0 + jl) * 3 + c];
        }
        __syncthreads();

        // S tiles: QK^T * scale + factorized geodesic bias
        f32x4 s[4];
        for (int tt = 0; tt < 4; tt++) {
            f32x4 acc = {};
            bf16x8 kb0 = *(const bf16x8*)&Klds[16 * tt + lo][8 * g];
            bf16x8 kb1 = *(const bf16x8*)&Klds[16 * tt + lo][32 + 8 * g];
            acc = mfma16(qa[0], kb0, acc);
            acc = mfma16(qa[1], kb1, acc);
            f32x4 ic[3];
            for (int c = 0; c < 3; c++) {
                bf16x8 xbf = {};
                if (g < 2) xbf = *(const bf16x8*)&Xlds[16 * tt + lo][c * 16 + 8 * g];
                f32x4 z = {};
                ic[c] = mfma16(xqa[c], xbf, z);
            }
            float B0 = Blds[0][16 * tt + lo];
            float B1 = Blds[1][16 * tt + lo];
            float B2 = Blds[2][16 * tt + lo];
            for (int r = 0; r < 4; r++) {
                float sv = acc[r] * SCALE;
                sv = fmaf(af[0][r] * B0, exp2f(k2[0] * ic[0][r]), sv);
                sv = fmaf(af[1][r] * B1, exp2f(k2[1] * ic[1][r]), sv);
                sv = fmaf(af[2][r] * B2, exp2f(k2[2] * ic[2][r]), sv);
                acc[r] = sv;
            }
            s[tt] = acc;
        }
        __syncthreads();   // all X reads done before P overlays the buffer

        // online softmax (rows live on 16-lane groups: row = 4g + r)
        float pm[4], sf[4], rs[4];
        for (int r = 0; r < 4; r++)
            pm[r] = fmaxf(fmaxf(s[0][r], s[1][r]), fmaxf(s[2][r], s[3][r]));
        for (int msk = 1; msk < 16; msk <<= 1)
            for (int r = 0; r < 4; r++) pm[r] = fmaxf(pm[r], __shfl_xor(pm[r], msk));
        for (int r = 0; r < 4; r++) {
            float mn = fmaxf(m_r[r], pm[r]);
            sf[r] = exp2f((m_r[r] - mn) * LOG2E);
            m_r[r] = mn;
            rs[r] = 0.0f;
        }
        for (int tt = 0; tt < 4; tt++)
            for (int r = 0; r < 4; r++) {
                float p = exp2f((s[tt][r] - m_r[r]) * LOG2E);
                s[tt][r] = p;
                rs[r] += p;
            }
        for (int msk = 1; msk < 16; msk <<= 1)
            for (int r = 0; r < 4; r++) rs[r] += __shfl_xor(rs[r], msk);
        for (int r = 0; r < 4; r++) l_r[r] = l_r[r] * sf[r] + rs[r];

        // P -> LDS (bf16), per-wave private region (aliases X tile)
        for (int tt = 0; tt < 4; tt++)
            for (int r = 0; r < 4; r++)
                Pw[(4 * g + r) * 72 + 16 * tt + lo] = (bf16)s[tt][r];

        for (int td = 0; td < 4; td++)
            for (int r = 0; r < 4; r++) o[td][r] *= sf[r];

        // PV: A = P (rows=lane&15), B = V^T (cols d = lane&15)
        bf16x8 pa0 = *(const bf16x8*)&Pw[lo * 72 + 8 * g];
        bf16x8 pa1 = *(const bf16x8*)&Pw[lo * 72 + 32 + 8 * g];
        for (int td = 0; td < 4; td++) {
            bf16x8 vb0 = *(const bf16x8*)&VTlds[16 * td + lo][8 * g];
            bf16x8 vb1 = *(const bf16x8*)&VTlds[16 * td + lo][32 + 8 * g];
            o[td] = mfma16(pa0, vb0, o[td]);
            o[td] = mfma16(pa1, vb1, o[td]);
        }
    }

    // write unnormalized partials
    for (int td = 0; td < 4; td++)
        for (int r = 0; r < 4; r++) {
            int i = i0 + 4 * g + r;
            size_t rowg = (size_t)(b * 8 + hh) * 1024 + i;
            o_part[((size_t)split * 32768 + rowg) * 64 + 16 * td + lo] = o[td][r];
        }
    if (lo == 0)
        for (int r = 0; r < 4; r++) {
            int i = i0 + 4 * g + r;
            size_t rowg = (size_t)(b * 8 + hh) * 1024 + i;
            ml_part[((size_t)split * 32768 + rowg) * 2]     = m_r[r];
            ml_part[((size_t)split * 32768 + rowg) * 2 + 1] = l_r[r];
        }
}

// -------------------------------------------------------------- merge -------
__global__ __launch_bounds__(256) void merge_kernel(
        const float* __restrict__ o_part, const float* __restrict__ ml_part,
        int nsplit, bf16* __restrict__ attnout) {
    int t = threadIdx.x;
    int rowg = blockIdx.x * 16 + (t >> 4);
    int d4 = (t & 15) * 4;
    float m0 = ml_part[(size_t)rowg * 2], l0 = ml_part[(size_t)rowg * 2 + 1];
    float m1 = -1e30f, l1 = 0.0f;
    if (nsplit == 2) {
        m1 = ml_part[((size_t)32768 + rowg) * 2];
        l1 = ml_part[((size_t)32768 + rowg) * 2 + 1];
    }
    float M = fmaxf(m0, m1);
    float w0 = exp2f((m0 - M) * LOG2E);
    float w1 = exp2f((m1 - M) * LOG2E);
    float inv = 1.0f / (w0 * l0 + w1 * l1);
    f32x4 a = *(const f32x4*)&o_part[(size_t)rowg * 64 + d4];
    f32x4 bv = (f32x4){0.f, 0.f, 0.f, 0.f};
    if (nsplit == 2) bv = *(const f32x4*)&o_part[((size_t)32768 + rowg) * 64 + d4];
    int b = rowg >> 13, hh = (rowg >> 10) & 7, i = rowg & 1023;
    bf16* dst = &attnout[((size_t)(b << 10) + i) * 512 + hh * 64 + d4];
    for (int q = 0; q < 4; q++)
        dst[q] = (bf16)((w0 * a[q] + w1 * bv[q]) * inv);
}

// ----------------------------------------------------- output GEMM ----------
__global__ __launch_bounds__(256) void gemm_out_kernel(
        const bf16* __restrict__ A, const bf16* __restrict__ Bm,
        const float* __restrict__ bias, float* __restrict__ out) {
    __shared__ bf16 Al[64][72];
    __shared__ bf16 Bl[64][72];
    int t = threadIdx.x;
    int w = t >> 6, lane = t & 63, g = lane >> 4, lo = lane & 15;
    int rowbase = blockIdx.x * 64, colbase = blockIdx.y * 64;
    int wr = (w >> 1) * 32, wc = (w & 1) * 32;
    f32x4 acc[2][2] = {};
    int sr = t >> 2, sc = (t & 3) * 16;
    for (int kb = 0; kb < 512; kb += 64) {
        *(bf16x8*)&Al[sr][sc]     = *(const bf16x8*)&A[(rowbase + sr) * 512 + kb + sc];
        *(bf16x8*)&Al[sr][sc + 8] = *(const bf16x8*)&A[(rowbase + sr) * 512 + kb + sc + 8];
        *(bf16x8*)&Bl[sr][sc]     = *(const bf16x8*)&Bm[(colbase + sr) * 512 + kb + sc];
        *(bf16x8*)&Bl[sr][sc + 8] = *(const bf16x8*)&Bm[(colbase + sr) * 512 + kb + sc + 8];
        __syncthreads();
        for (int kk = 0; kk < 64; kk += 32) {
            bf16x8 af[2], bfr[2];
            af[0]  = *(const bf16x8*)&Al[wr + lo][kk + 8 * g];
            af[1]  = *(const bf16x8*)&Al[wr + 16 + lo][kk + 8 * g];
            bfr[0] = *(const bf16x8*)&Bl[wc + lo][kk + 8 * g];
            bfr[1] = *(const bf16x8*)&Bl[wc + 16 + lo][kk + 8 * g];
            for (int ri = 0; ri < 2; ri++)
                for (int ci = 0; ci < 2; ci++)
                    acc[ri][ci] = mfma16(af[ri], bfr[ci], acc[ri][ci]);
        }
        __syncthreads();
    }
    for (int ri = 0; ri < 2; ri++)
        for (int ci = 0; ci < 2; ci++) {
            int mcol = colbase + wc + 16 * ci + lo;
            float bv = bias[mcol];
            for (int r = 0; r < 4; r++) {
                int n = rowbase + wr + 16 * ri + 4 * g + r;
                out[(size_t)n * 512 + mcol] = acc[ri][ci][r] + bv;
            }
        }
}

// ---------------------------------------------------------------- launch ----
extern "C" void kernel_launch(void* const* d_in, const int* in_sizes, int n_in,
                              void* d_out, int out_size, void* d_ws, size_t ws_size,
                              hipStream_t stream) {
    const float* h  = (const float*)d_in[0];
    const float* x  = (const float*)d_in[1];
    const float* Wq = (const float*)d_in[2];
    const float* bq = (const float*)d_in[3];
    const float* Wk = (const float*)d_in[4];
    const float* bk = (const float*)d_in[5];
    const float* Wv = (const float*)d_in[6];
    const float* bv = (const float*)d_in[7];
    const float* Wo = (const float*)d_in[8];
    const float* bo = (const float*)d_in[9];
    const float* alpha     = (const float*)d_in[10];
    const float* log_sigma = (const float*)d_in[11];
    float* out = (float*)d_out;

    char* ws = (char*)d_ws;
    size_t off = 0;
    auto alloc = [&](size_t bytes) {
        char* p = ws + off;
        off += (bytes + 255) & ~(size_t)255;
        return p;
    };
    bf16*  hb      = (bf16*)alloc(4096 * 512 * 2);
    bf16*  wpack   = (bf16*)alloc(1536 * 512 * 2);
    bf16*  wob     = (bf16*)alloc(512 * 512 * 2);
    float* bqkv    = (float*)alloc(1536 * 4);
    bf16*  xb      = (bf16*)alloc(4096 * 48 * 2);
    float* Aexp    = (float*)alloc((size_t)4096 * 8 * 3 * 4);
    float* Bexp    = (float*)alloc((size_t)4096 * 8 * 3 * 4);
    bf16*  Qb      = (bf16*)alloc((size_t)4 * 8 * 1024 * 64 * 2);
    bf16*  Kb      = (bf16*)alloc((size_t)4 * 8 * 1024 * 64 * 2);
    bf16*  Vt      = (bf16*)alloc((size_t)4 * 8 * 1024 * 64 * 2);
    bf16*  attnout = (bf16*)alloc(4096 * 512 * 2);
    size_t base = off;

    // KV-split partials: o (f32) + (m,l) per row per split
    size_t need2 = base + 2 * ((size_t)32768 * 64 * 4 + 1024) + 2 * ((size_t)32768 * 2 * 4 + 1024);
    int nsplit = (ws_size >= need2) ? 2 : 1;
    float* o_part  = (float*)alloc((size_t)nsplit * 32768 * 64 * 4);
    float* ml_part = (float*)alloc((size_t)nsplit * 32768 * 2 * 4);

    prep_kernel<<<512, 256, 0, stream>>>(h, x, Wq, Wk, Wv, Wo, bq, bk, bv,
                                         alpha, log_sigma,
                                         hb, wpack, wob, bqkv, xb, Aexp, Bexp);
    gemm_qkv_kernel<<<dim3(64, 24), 256, 0, stream>>>(hb, wpack, bqkv, Qb, Kb, Vt);
    attn_kernel<<<dim3(16, 8, 4 * nsplit), 256, 0, stream>>>(
        Qb, Kb, Vt, xb, Aexp, Bexp, log_sigma, nsplit, o_part, ml_part);
    merge_kernel<<<2048, 256, 0, stream>>>(o_part, ml_part, nsplit, attnout);
    gemm_out_kernel<<<dim3(64, 8), 256, 0, stream>>>(attnout, wob, bo, out);
}

// Round 6
// 172.570 us; speedup vs baseline: 1.2226x; 1.1634x over previous
//
#include <hip/hip_runtime.h>
#include <math.h>

typedef __bf16 bf16;
typedef __attribute__((ext_vector_type(8))) __bf16 bf16x8;
typedef __attribute__((ext_vector_type(4))) float f32x4;

#define LOG2E 1.44269504088896f
#define SCALE 0.125f   // 1/sqrt(64)

__device__ inline f32x4 mfma16(bf16x8 a, bf16x8 b, f32x4 c) {
    return __builtin_amdgcn_mfma_f32_16x16x32_bf16(a, b, c, 0, 0, 0);
}
__device__ inline unsigned short bfb(bf16 v) {
    union { bf16 b; unsigned short u; } z; z.b = v; return z.u;
}

// ---------------------------------------------------------------- prep ------
// bf16 conversions + packed QKV weights + spack[row,c] = hi/lo bf16 pair of
// s = -|x_row,c|^2 / 2  (sigma- and head-independent).  In the geo MFMA,
// K-slots pair A:[s_hi,s_lo,1,1] with B:[1,1,s_hi,s_lo] so the MFMA emits
// u = <xi,xj> - |xi|^2/2 - |xj|^2/2 = -d^2/2 directly.
__global__ __launch_bounds__(256) void prep_kernel(
        const float* __restrict__ h, const float* __restrict__ x,
        const float* __restrict__ Wq, const float* __restrict__ Wk,
        const float* __restrict__ Wv, const float* __restrict__ Wo,
        const float* __restrict__ bq, const float* __restrict__ bk,
        const float* __restrict__ bv,
        bf16* __restrict__ hb, bf16* __restrict__ wpack, bf16* __restrict__ wob,
        float* __restrict__ bqkv, bf16* __restrict__ xb,
        unsigned* __restrict__ spack) {
    int stride = gridDim.x * blockDim.x;
    int tid = blockIdx.x * blockDim.x + threadIdx.x;
    for (int i = tid; i < 4096 * 512; i += stride) hb[i] = (bf16)h[i];
    for (int i = tid; i < 262144; i += stride) {
        wpack[i]          = (bf16)Wq[i];
        wpack[262144 + i] = (bf16)Wk[i];
        wpack[524288 + i] = (bf16)Wv[i];
    }
    for (int i = tid; i < 512 * 512; i += stride) wob[i] = (bf16)Wo[i];
    for (int i = tid; i < 1536; i += stride)
        bqkv[i] = (i < 512) ? bq[i] : (i < 1024 ? bk[i - 512] : bv[i - 1024]);
    for (int i = tid; i < 4096 * 48; i += stride) xb[i] = (bf16)x[i];
    for (int i = tid; i < 4096 * 3; i += stride) {
        int row = i / 3, c = i - row * 3;
        float s = 0.0f;
        for (int k = 0; k < 16; k++) {
            float v = (float)(bf16)x[row * 48 + c * 16 + k];
            s += v * v;
        }
        s = -0.5f * s;
        bf16 sh = (bf16)s;
        bf16 sl = (bf16)(s - (float)sh);
        spack[i] = (unsigned)bfb(sh) | ((unsigned)bfb(sl) << 16);
    }
}

// ---------------------------------------------------------- QKV GEMM --------
// 128x128 tile, 4 waves (2x2 quadrants of 64x64), BK=64, K=512.
// Q,K -> (B,H,N,64); V -> transposed (B,H,64,N). Epilogue through LDS.
__global__ __launch_bounds__(256) void gemm_qkv_kernel(
        const bf16* __restrict__ A, const bf16* __restrict__ Bm,
        const float* __restrict__ bias,
        bf16* __restrict__ Qb, bf16* __restrict__ Kb, bf16* __restrict__ Vt) {
    __shared__ bf16 smem[2 * 128 * 72];
    bf16 (*Asm)[72] = (bf16(*)[72])smem;
    bf16 (*Bsm)[72] = (bf16(*)[72])(smem + 128 * 72);
    int t = threadIdx.x, w = t >> 6, lane = t & 63, g = lane >> 4, lo = lane & 15;
    int rowbase = blockIdx.x * 128, colbase = blockIdx.y * 128;
    int wr = (w >> 1) * 64, wc = (w & 1) * 64;
    f32x4 acc[4][4] = {};
    int srow = t >> 2, scol = (t & 3) * 16;
    for (int kb = 0; kb < 512; kb += 64) {
        __syncthreads();
        for (int half = 0; half < 2; half++) {
            int r = srow + 64 * half;
            *(bf16x8*)&Asm[r][scol]     = *(const bf16x8*)&A[(size_t)(rowbase + r) * 512 + kb + scol];
            *(bf16x8*)&Asm[r][scol + 8] = *(const bf16x8*)&A[(size_t)(rowbase + r) * 512 + kb + scol + 8];
            *(bf16x8*)&Bsm[r][scol]     = *(const bf16x8*)&Bm[(size_t)(colbase + r) * 512 + kb + scol];
            *(bf16x8*)&Bsm[r][scol + 8] = *(const bf16x8*)&Bm[(size_t)(colbase + r) * 512 + kb + scol + 8];
        }
        __syncthreads();
        for (int kk = 0; kk < 64; kk += 32) {
            bf16x8 af[4], bfr[4];
            for (int m = 0; m < 4; m++) af[m]  = *(const bf16x8*)&Asm[wr + 16 * m + lo][kk + 8 * g];
            for (int n = 0; n < 4; n++) bfr[n] = *(const bf16x8*)&Bsm[wc + 16 * n + lo][kk + 8 * g];
            for (int m = 0; m < 4; m++)
                for (int n = 0; n < 4; n++)
                    acc[m][n] = mfma16(af[m], bfr[n], acc[m][n]);
        }
    }
    __syncthreads();
    bf16 (*Cl)[132] = (bf16(*)[132])smem;
    for (int n = 0; n < 4; n++) {
        float bv = bias[colbase + wc + 16 * n + lo];
        for (int m = 0; m < 4; m++)
            for (int r = 0; r < 4; r++)
                Cl[wr + 16 * m + 4 * g + r][wc + 16 * n + lo] = (bf16)(acc[m][n][r] + bv);
    }
    __syncthreads();
    int proj = colbase >> 9, h0 = (colbase >> 6) & 7;
    int bidx = rowbase >> 10, i0g = rowbase & 1023;
    if (proj < 2) {
        int row = t >> 1, half = t & 1;
        bf16* dst = (proj == 0 ? Qb : Kb) +
                    ((size_t)(bidx * 8 + h0 + half) * 1024 + i0g + row) * 64;
        for (int ch = 0; ch < 8; ch++)
            *(bf16x8*)&dst[ch * 8] = *(const bf16x8*)&Cl[row][half * 64 + ch * 8];
    } else {
        int dcol = t >> 1, ihalf = t & 1;
        int head = h0 + (dcol >> 6), d = dcol & 63;
        bf16* dst = Vt + ((size_t)(bidx * 8 + head) * 64 + d) * 1024 + i0g + ihalf * 64;
        for (int ch = 0; ch < 8; ch++) {
            bf16x8 v;
            for (int q = 0; q < 8; q++) v[q] = Cl[ihalf * 64 + ch * 8 + q][dcol];
            *(bf16x8*)&dst[ch * 8] = v;
        }
    }
}

// ----------------------------------------------------- fused attention ------
// Fixed-max flash attention (S bounded -> no online softmax).
// geo MFMA emits u = -d^2/2; bias = sum_c alpha_c * e^(u/sigma_c^2), with the
// clamp u<=0 matching the reference's max(d^2,0). Row sums via ones-MFMA.
__global__ __launch_bounds__(256) void attn_kernel(
        const bf16* __restrict__ Qb, const bf16* __restrict__ Kb,
        const bf16* __restrict__ Vt, const bf16* __restrict__ xb,
        const unsigned* __restrict__ spack,
        const float* __restrict__ alpha, const float* __restrict__ log_sigma,
        int nsplit, float* __restrict__ o_part, float* __restrict__ l_part) {
    __shared__ bf16 Klds[64][72];
    __shared__ bf16 VTlds[64][72];
    __shared__ bf16 Xlds[64][104];   // comp c at cols c*32: 16 x, 4 consts, 12 zeros
    __shared__ bf16 Plds[4][16][72];

    int t = threadIdx.x;
    int w = t >> 6, lane = t & 63, g = lane >> 4, lo = lane & 15;
    int zz = blockIdx.z;
    int b = zz / nsplit, split = zz - b * nsplit;
    int hh = blockIdx.y;
    int i0 = blockIdx.x * 64 + w * 16;

    const unsigned ONE2 = 0x3F803F80u;
    float c1 = SCALE * LOG2E;
    float k2[3], alf[3];
    for (int c = 0; c < 3; c++) {
        float sg = fmaxf(expf(log_sigma[hh * 3 + c]), 1e-4f);
        k2[c] = LOG2E / (sg * sg);
        alf[c] = alpha[hh * 3 + c] * LOG2E;
    }

    const bf16* Qbase = Qb + ((size_t)(b * 8 + hh) * 1024 + i0) * 64;
    bf16x8 qa[2];
    qa[0] = *(const bf16x8*)&Qbase[lo * 64 + 8 * g];
    qa[1] = *(const bf16x8*)&Qbase[lo * 64 + 32 + 8 * g];

    // A-side geo fragments: g<2: raw bf16 x; g==2: [s_hi,s_lo,1,1,0..]; g==3: 0
    bf16x8 xqa[3];
    for (int c = 0; c < 3; c++) {
        bf16x8 v = {};
        if (g < 2) {
            v = *(const bf16x8*)&xb[((size_t)(b << 10) + i0 + lo) * 48 + c * 16 + 8 * g];
        } else if (g == 2) {
            uint2 ap;
            ap.x = spack[((size_t)(b << 10) + i0 + lo) * 3 + c];
            ap.y = ONE2;
            ((uint2*)&v)[0] = ap;
        }
        xqa[c] = v;
    }

    bf16x8 ones;
    for (int e = 0; e < 8; e++) ones[e] = (bf16)1.0f;
    f32x4 o[4] = {};
    f32x4 lacc = {};

    // zero Xlds once (pad zeros at cols c*32+20..31 persist across tiles)
    for (int idx = t; idx < 1664; idx += 256)
        ((unsigned long long*)&Xlds[0][0])[idx] = 0ULL;

    int sr = t >> 2, sc = (t & 3) * 16;
    int jlen = 1024 / nsplit, jb = split * jlen;
    for (int j0 = jb; j0 < jb + jlen; j0 += 64) {
        __syncthreads();   // prev tile reads done (covers zero-init on iter 0)
        const bf16* Kbase = Kb + ((size_t)(b * 8 + hh) * 1024 + j0) * 64;
        *(bf16x8*)&Klds[sr][sc]     = *(const bf16x8*)&Kbase[sr * 64 + sc];
        *(bf16x8*)&Klds[sr][sc + 8] = *(const bf16x8*)&Kbase[sr * 64 + sc + 8];
        const bf16* Vbase = Vt + ((size_t)(b * 8 + hh) * 64) * 1024 + j0;
        *(bf16x8*)&VTlds[sr][sc]     = *(const bf16x8*)&Vbase[sr * 1024 + sc];
        *(bf16x8*)&VTlds[sr][sc + 8] = *(const bf16x8*)&Vbase[sr * 1024 + sc + 8];
        if (t < 192) {
            int xr = t / 3, c = t - xr * 3;
            const bf16* xsrc = &xb[((size_t)(b << 10) + j0 + xr) * 48 + c * 16];
            *(bf16x8*)&Xlds[xr][c * 32]     = *(const bf16x8*)&xsrc[0];
            *(bf16x8*)&Xlds[xr][c * 32 + 8] = *(const bf16x8*)&xsrc[8];
            uint2 bp;
            bp.x = ONE2;
            bp.y = spack[((size_t)(b << 10) + j0 + xr) * 3 + c];
            *(uint2*)&Xlds[xr][c * 32 + 16] = bp;
        }
        __syncthreads();

        for (int tt = 0; tt < 4; tt++) {
            f32x4 acc = {};
            bf16x8 kb0 = *(const bf16x8*)&Klds[16 * tt + lo][8 * g];
            bf16x8 kb1 = *(const bf16x8*)&Klds[16 * tt + lo][32 + 8 * g];
            acc = mfma16(qa[0], kb0, acc);
            acc = mfma16(qa[1], kb1, acc);
            f32x4 z0 = {}, z1 = {}, z2 = {};
            f32x4 e0 = mfma16(xqa[0], *(const bf16x8*)&Xlds[16 * tt + lo][8 * g], z0);
            f32x4 e1 = mfma16(xqa[1], *(const bf16x8*)&Xlds[16 * tt + lo][32 + 8 * g], z1);
            f32x4 e2 = mfma16(xqa[2], *(const bf16x8*)&Xlds[16 * tt + lo][64 + 8 * g], z2);
            for (int r = 0; r < 4; r++) {
                float t0 = alf[0] * exp2f(k2[0] * fminf(e0[r], 0.0f));
                t0 = fmaf(alf[1], exp2f(k2[1] * fminf(e1[r], 0.0f)), t0);
                t0 = fmaf(alf[2], exp2f(k2[2] * fminf(e2[r], 0.0f)), t0);
                float p = exp2f(fmaf(acc[r], c1, t0));
                Plds[w][4 * g + r][16 * tt + lo] = (bf16)p;
            }
        }

        bf16x8 pa0 = *(const bf16x8*)&Plds[w][lo][8 * g];
        bf16x8 pa1 = *(const bf16x8*)&Plds[w][lo][32 + 8 * g];
        lacc = mfma16(pa0, ones, lacc);
        lacc = mfma16(pa1, ones, lacc);
        for (int td = 0; td < 4; td++) {
            bf16x8 vb0 = *(const bf16x8*)&VTlds[16 * td + lo][8 * g];
            bf16x8 vb1 = *(const bf16x8*)&VTlds[16 * td + lo][32 + 8 * g];
            o[td] = mfma16(pa0, vb0, o[td]);
            o[td] = mfma16(pa1, vb1, o[td]);
        }
    }

    for (int td = 0; td < 4; td++)
        for (int r = 0; r < 4; r++) {
            size_t rowg = (size_t)(b * 8 + hh) * 1024 + i0 + 4 * g + r;
            o_part[((size_t)split * 32768 + rowg) * 64 + 16 * td + lo] = o[td][r];
        }
    if (lo == 0)
        for (int r = 0; r < 4; r++) {
            size_t rowg = (size_t)(b * 8 + hh) * 1024 + i0 + 4 * g + r;
            l_part[(size_t)split * 32768 + rowg] = lacc[r];
        }
}

// -------------------------------------------------------------- merge -------
__global__ __launch_bounds__(256) void merge_kernel(
        const float* __restrict__ o_part, const float* __restrict__ l_part,
        int nsplit, bf16* __restrict__ attnout) {
    int t = threadIdx.x;
    int rowg = blockIdx.x * 16 + (t >> 4);
    int d4 = (t & 15) * 4;
    float l = l_part[rowg];
    f32x4 a = *(const f32x4*)&o_part[(size_t)rowg * 64 + d4];
    if (nsplit == 2) {
        l += l_part[32768 + rowg];
        f32x4 b2 = *(const f32x4*)&o_part[((size_t)32768 + rowg) * 64 + d4];
        for (int q = 0; q < 4; q++) a[q] += b2[q];
    }
    float inv = 1.0f / l;
    int b = rowg >> 13, hh = (rowg >> 10) & 7, i = rowg & 1023;
    bf16* dst = &attnout[((size_t)(b << 10) + i) * 512 + hh * 64 + d4];
    for (int q = 0; q < 4; q++) dst[q] = (bf16)(a[q] * inv);
}

// ----------------------------------------------------- output GEMM ----------
// 128x128 tile, same structure as QKV GEMM, direct f32 epilogue.
__global__ __launch_bounds__(256) void gemm_out_kernel(
        const bf16* __restrict__ A, const bf16* __restrict__ Bm,
        const float* __restrict__ bias, float* __restrict__ out) {
    __shared__ bf16 smem[2 * 128 * 72];
    bf16 (*Asm)[72] = (bf16(*)[72])smem;
    bf16 (*Bsm)[72] = (bf16(*)[72])(smem + 128 * 72);
    int t = threadIdx.x, w = t >> 6, lane = t & 63, g = lane >> 4, lo = lane & 15;
    int rowbase = blockIdx.x * 128, colbase = blockIdx.y * 128;
    int wr = (w >> 1) * 64, wc = (w & 1) * 64;
    f32x4 acc[4][4] = {};
    int srow = t >> 2, scol = (t & 3) * 16;
    for (int kb = 0; kb < 512; kb += 64) {
        __syncthreads();
        for (int half = 0; half < 2; half++) {
            int r = srow + 64 * half;
            *(bf16x8*)&Asm[r][scol]     = *(const bf16x8*)&A[(size_t)(rowbase + r) * 512 + kb + scol];
            *(bf16x8*)&Asm[r][scol + 8] = *(const bf16x8*)&A[(size_t)(rowbase + r) * 512 + kb + scol + 8];
            *(bf16x8*)&Bsm[r][scol]     = *(const bf16x8*)&Bm[(size_t)(colbase + r) * 512 + kb + scol];
            *(bf16x8*)&Bsm[r][scol + 8] = *(const bf16x8*)&Bm[(size_t)(colbase + r) * 512 + kb + scol + 8];
        }
        __syncthreads();
        for (int kk = 0; kk < 64; kk += 32) {
            bf16x8 af[4], bfr[4];
            for (int m = 0; m < 4; m++) af[m]  = *(const bf16x8*)&Asm[wr + 16 * m + lo][kk + 8 * g];
            for (int n = 0; n < 4; n++) bfr[n] = *(const bf16x8*)&Bsm[wc + 16 * n + lo][kk + 8 * g];
            for (int m = 0; m < 4; m++)
                for (int n = 0; n < 4; n++)
                    acc[m][n] = mfma16(af[m], bfr[n], acc[m][n]);
        }
    }
    for (int n = 0; n < 4; n++) {
        int mcol = colbase + wc + 16 * n + lo;
        float bv = bias[mcol];
        for (int m = 0; m < 4; m++)
            for (int r = 0; r < 4; r++)
                out[(size_t)(rowbase + wr + 16 * m + 4 * g + r) * 512 + mcol] =
                    acc[m][n][r] + bv;
    }
}

// ---------------------------------------------------------------- launch ----
extern "C" void kernel_launch(void* const* d_in, const int* in_sizes, int n_in,
                              void* d_out, int out_size, void* d_ws, size_t ws_size,
                              hipStream_t stream) {
    const float* h  = (const float*)d_in[0];
    const float* x  = (const float*)d_in[1];
    const float* Wq = (const float*)d_in[2];
    const float* bq = (const float*)d_in[3];
    const float* Wk = (const float*)d_in[4];
    const float* bk = (const float*)d_in[5];
    const float* Wv = (const float*)d_in[6];
    const float* bv = (const float*)d_in[7];
    const float* Wo = (const float*)d_in[8];
    const float* bo = (const float*)d_in[9];
    const float* alpha     = (const float*)d_in[10];
    const float* log_sigma = (const float*)d_in[11];
    float* out = (float*)d_out;

    char* ws = (char*)d_ws;
    size_t off = 0;
    auto alloc = [&](size_t bytes) {
        char* p = ws + off;
        off += (bytes + 255) & ~(size_t)255;
        return p;
    };
    bf16*     hb      = (bf16*)alloc(4096 * 512 * 2);
    bf16*     wpack   = (bf16*)alloc(1536 * 512 * 2);
    bf16*     wob     = (bf16*)alloc(512 * 512 * 2);
    float*    bqkv    = (float*)alloc(1536 * 4);
    bf16*     xb      = (bf16*)alloc(4096 * 48 * 2);
    unsigned* spack   = (unsigned*)alloc((size_t)4096 * 3 * 4);
    bf16*     Qb      = (bf16*)alloc((size_t)4 * 8 * 1024 * 64 * 2);
    bf16*     Kb      = (bf16*)alloc((size_t)4 * 8 * 1024 * 64 * 2);
    bf16*     Vt      = (bf16*)alloc((size_t)4 * 8 * 1024 * 64 * 2);
    bf16*     attnout = (bf16*)alloc(4096 * 512 * 2);
    size_t base = off;

    size_t need2 = base + 2 * ((size_t)32768 * 64 * 4 + 1024) + 2 * ((size_t)32768 * 4 + 1024);
    int nsplit = (ws_size >= need2) ? 2 : 1;
    float* o_part = (float*)alloc((size_t)nsplit * 32768 * 64 * 4);
    float* l_part = (float*)alloc((size_t)nsplit * 32768 * 4);

    prep_kernel<<<512, 256, 0, stream>>>(h, x, Wq, Wk, Wv, Wo, bq, bk, bv,
                                         hb, wpack, wob, bqkv, xb, spack);
    gemm_qkv_kernel<<<dim3(32, 12), 256, 0, stream>>>(hb, wpack, bqkv, Qb, Kb, Vt);
    attn_kernel<<<dim3(16, 8, 4 * nsplit), 256, 0, stream>>>(
        Qb, Kb, Vt, xb, spack, alpha, log_sigma, nsplit, o_part, l_part);
    merge_kernel<<<2048, 256, 0, stream>>>(o_part, l_part, nsplit, attnout);
    gemm_out_kernel<<<dim3(32, 4), 256, 0, stream>>>(attnout, wob, bo, out);
}

// Round 7
// 171.326 us; speedup vs baseline: 1.2315x; 1.0073x over previous
//
#include <hip/hip_runtime.h>
#include <math.h>

typedef __bf16 bf16;
typedef __attribute__((ext_vector_type(8))) __bf16 bf16x8;
typedef __attribute__((ext_vector_type(4))) float f32x4;

#define LOG2E 1.44269504088896f
#define SCALE 0.125f   // 1/sqrt(64)

__device__ inline f32x4 mfma16(bf16x8 a, bf16x8 b, f32x4 c) {
    return __builtin_amdgcn_mfma_f32_16x16x32_bf16(a, b, c, 0, 0, 0);
}
__device__ inline unsigned short bfb(bf16 v) {
    union { bf16 b; unsigned short u; } z; z.b = v; return z.u;
}
__device__ inline bf16x8 cvt8(float4 v0, float4 v1) {
    bf16x8 o;
    o[0] = (bf16)v0.x; o[1] = (bf16)v0.y; o[2] = (bf16)v0.z; o[3] = (bf16)v0.w;
    o[4] = (bf16)v1.x; o[5] = (bf16)v1.y; o[6] = (bf16)v1.z; o[7] = (bf16)v1.w;
    return o;
}

// ---------------------------------------------------------------- prep ------
// Vectorized bf16 conversions + packed QKV weights + spack[row,c] = hi/lo bf16
// pair of s = -|x_row,c|^2/2. In the geo MFMA, K-slots pair A:[s_hi,s_lo,1,1]
// with B:[1,1,s_hi,s_lo] so the MFMA emits u = <xi,xj> - |xi|^2/2 - |xj|^2/2
// = -d^2/2 directly.
__global__ __launch_bounds__(256) void prep_kernel(
        const float* __restrict__ h, const float* __restrict__ x,
        const float* __restrict__ Wq, const float* __restrict__ Wk,
        const float* __restrict__ Wv, const float* __restrict__ Wo,
        const float* __restrict__ bq, const float* __restrict__ bk,
        const float* __restrict__ bv,
        bf16* __restrict__ hb, bf16* __restrict__ wpack, bf16* __restrict__ wob,
        float* __restrict__ bqkv, bf16* __restrict__ xb,
        unsigned* __restrict__ spack) {
    int stride = gridDim.x * blockDim.x;
    int tid = blockIdx.x * blockDim.x + threadIdx.x;
    for (int i = tid; i < 262144; i += stride) {   // h: 2M elems, x8
        const float4* s = (const float4*)h + 2 * i;
        ((bf16x8*)hb)[i] = cvt8(s[0], s[1]);
    }
    for (int i = tid; i < 32768; i += stride) {    // each W: 262144, x8
        const float4* sq = (const float4*)Wq + 2 * i;
        const float4* sk = (const float4*)Wk + 2 * i;
        const float4* sv = (const float4*)Wv + 2 * i;
        const float4* so = (const float4*)Wo + 2 * i;
        ((bf16x8*)wpack)[i]         = cvt8(sq[0], sq[1]);
        ((bf16x8*)wpack)[32768 + i] = cvt8(sk[0], sk[1]);
        ((bf16x8*)wpack)[65536 + i] = cvt8(sv[0], sv[1]);
        ((bf16x8*)wob)[i]           = cvt8(so[0], so[1]);
    }
    for (int i = tid; i < 24576; i += stride) {    // x: 196608, x8
        const float4* s = (const float4*)x + 2 * i;
        ((bf16x8*)xb)[i] = cvt8(s[0], s[1]);
    }
    for (int i = tid; i < 1536; i += stride)
        bqkv[i] = (i < 512) ? bq[i] : (i < 1024 ? bk[i - 512] : bv[i - 1024]);
    for (int i = tid; i < 4096 * 3; i += stride) {
        int row = i / 3, c = i - row * 3;
        float s = 0.0f;
        for (int k = 0; k < 16; k++) {
            float v = (float)(bf16)x[row * 48 + c * 16 + k];
            s += v * v;
        }
        s = -0.5f * s;
        bf16 sh = (bf16)s;
        bf16 sl = (bf16)(s - (float)sh);
        spack[i] = (unsigned)bfb(sh) | ((unsigned)bfb(sl) << 16);
    }
}

// ---------------------------------------------------------- QKV GEMM --------
// 128x128 tile, 4 waves (2x2 quadrants of 64x64), BK=64, K=512.
// Q,K -> (B,H,N,64); V -> transposed (B,H,64,N). Epilogue through LDS.
__global__ __launch_bounds__(256) void gemm_qkv_kernel(
        const bf16* __restrict__ A, const bf16* __restrict__ Bm,
        const float* __restrict__ bias,
        bf16* __restrict__ Qb, bf16* __restrict__ Kb, bf16* __restrict__ Vt) {
    __shared__ bf16 smem[2 * 128 * 72];
    bf16 (*Asm)[72] = (bf16(*)[72])smem;
    bf16 (*Bsm)[72] = (bf16(*)[72])(smem + 128 * 72);
    int t = threadIdx.x, w = t >> 6, lane = t & 63, g = lane >> 4, lo = lane & 15;
    int rowbase = blockIdx.x * 128, colbase = blockIdx.y * 128;
    int wr = (w >> 1) * 64, wc = (w & 1) * 64;
    f32x4 acc[4][4] = {};
    int srow = t >> 2, scol = (t & 3) * 16;
    for (int kb = 0; kb < 512; kb += 64) {
        __syncthreads();
        for (int half = 0; half < 2; half++) {
            int r = srow + 64 * half;
            *(bf16x8*)&Asm[r][scol]     = *(const bf16x8*)&A[(size_t)(rowbase + r) * 512 + kb + scol];
            *(bf16x8*)&Asm[r][scol + 8] = *(const bf16x8*)&A[(size_t)(rowbase + r) * 512 + kb + scol + 8];
            *(bf16x8*)&Bsm[r][scol]     = *(const bf16x8*)&Bm[(size_t)(colbase + r) * 512 + kb + scol];
            *(bf16x8*)&Bsm[r][scol + 8] = *(const bf16x8*)&Bm[(size_t)(colbase + r) * 512 + kb + scol + 8];
        }
        __syncthreads();
        for (int kk = 0; kk < 64; kk += 32) {
            bf16x8 af[4], bfr[4];
            for (int m = 0; m < 4; m++) af[m]  = *(const bf16x8*)&Asm[wr + 16 * m + lo][kk + 8 * g];
            for (int n = 0; n < 4; n++) bfr[n] = *(const bf16x8*)&Bsm[wc + 16 * n + lo][kk + 8 * g];
            for (int m = 0; m < 4; m++)
                for (int n = 0; n < 4; n++)
                    acc[m][n] = mfma16(af[m], bfr[n], acc[m][n]);
        }
    }
    __syncthreads();
    bf16 (*Cl)[132] = (bf16(*)[132])smem;
    for (int n = 0; n < 4; n++) {
        float bv = bias[colbase + wc + 16 * n + lo];
        for (int m = 0; m < 4; m++)
            for (int r = 0; r < 4; r++)
                Cl[wr + 16 * m + 4 * g + r][wc + 16 * n + lo] = (bf16)(acc[m][n][r] + bv);
    }
    __syncthreads();
    int proj = colbase >> 9, h0 = (colbase >> 6) & 7;
    int bidx = rowbase >> 10, i0g = rowbase & 1023;
    if (proj < 2) {
        int row = t >> 1, half = t & 1;
        bf16* dst = (proj == 0 ? Qb : Kb) +
                    ((size_t)(bidx * 8 + h0 + half) * 1024 + i0g + row) * 64;
        for (int ch = 0; ch < 8; ch++)
            *(bf16x8*)&dst[ch * 8] = *(const bf16x8*)&Cl[row][half * 64 + ch * 8];
    } else {
        int dcol = t >> 1, ihalf = t & 1;
        int head = h0 + (dcol >> 6), d = dcol & 63;
        bf16* dst = Vt + ((size_t)(bidx * 8 + head) * 64 + d) * 1024 + i0g + ihalf * 64;
        for (int ch = 0; ch < 8; ch++) {
            bf16x8 v;
            for (int q = 0; q < 8; q++) v[q] = Cl[ihalf * 64 + ch * 8 + q][dcol];
            *(bf16x8*)&dst[ch * 8] = v;
        }
    }
}

// ----------------------------------------------------- fused attention ------
// Fixed-max flash attention (S bounded -> no online softmax, no KV-split).
// geo MFMA emits u = -d^2/2; bias = sum_c alpha_c * e^(u/sigma_c^2), clamp
// u<=0 matches reference's max(d^2,0). Row sums via ones-MFMA; normalized
// bf16 output written directly.
__global__ __launch_bounds__(256) void attn_kernel(
        const bf16* __restrict__ Qb, const bf16* __restrict__ Kb,
        const bf16* __restrict__ Vt, const bf16* __restrict__ xb,
        const unsigned* __restrict__ spack,
        const float* __restrict__ alpha, const float* __restrict__ log_sigma,
        bf16* __restrict__ attnout) {
    __shared__ bf16 Klds[64][72];
    __shared__ bf16 VTlds[64][72];
    __shared__ bf16 Xlds[64][104];   // comp c at cols c*32: 16 x, 4 consts, 12 zeros
    __shared__ bf16 Plds[4][16][72];

    int t = threadIdx.x;
    int w = t >> 6, lane = t & 63, g = lane >> 4, lo = lane & 15;
    int b = blockIdx.z;
    int hh = blockIdx.y;
    int i0 = blockIdx.x * 64 + w * 16;

    const unsigned ONE2 = 0x3F803F80u;
    float c1 = SCALE * LOG2E;
    float k2[3], alf[3];
    for (int c = 0; c < 3; c++) {
        float sg = fmaxf(expf(log_sigma[hh * 3 + c]), 1e-4f);
        k2[c] = LOG2E / (sg * sg);
        alf[c] = alpha[hh * 3 + c] * LOG2E;
    }

    const bf16* Qbase = Qb + ((size_t)(b * 8 + hh) * 1024 + i0) * 64;
    bf16x8 qa[2];
    qa[0] = *(const bf16x8*)&Qbase[lo * 64 + 8 * g];
    qa[1] = *(const bf16x8*)&Qbase[lo * 64 + 32 + 8 * g];

    // A-side geo fragments: g<2: raw bf16 x; g==2: [s_hi,s_lo,1,1,0..]; g==3: 0
    bf16x8 xqa[3];
    for (int c = 0; c < 3; c++) {
        bf16x8 v = {};
        if (g < 2) {
            v = *(const bf16x8*)&xb[((size_t)(b << 10) + i0 + lo) * 48 + c * 16 + 8 * g];
        } else if (g == 2) {
            uint2 ap;
            ap.x = spack[((size_t)(b << 10) + i0 + lo) * 3 + c];
            ap.y = ONE2;
            ((uint2*)&v)[0] = ap;
        }
        xqa[c] = v;
    }

    bf16x8 ones;
    for (int e = 0; e < 8; e++) ones[e] = (bf16)1.0f;
    f32x4 o[4] = {};
    f32x4 lacc = {};

    // zero Xlds once (pad zeros at cols c*32+20..31 persist across tiles)
    for (int idx = t; idx < 1664; idx += 256)
        ((unsigned long long*)&Xlds[0][0])[idx] = 0ULL;

    int sr = t >> 2, sc = (t & 3) * 16;
    for (int j0 = 0; j0 < 1024; j0 += 64) {
        __syncthreads();   // prev tile reads done (covers zero-init on iter 0)
        const bf16* Kbase = Kb + ((size_t)(b * 8 + hh) * 1024 + j0) * 64;
        *(bf16x8*)&Klds[sr][sc]     = *(const bf16x8*)&Kbase[sr * 64 + sc];
        *(bf16x8*)&Klds[sr][sc + 8] = *(const bf16x8*)&Kbase[sr * 64 + sc + 8];
        const bf16* Vbase = Vt + ((size_t)(b * 8 + hh) * 64) * 1024 + j0;
        *(bf16x8*)&VTlds[sr][sc]     = *(const bf16x8*)&Vbase[sr * 1024 + sc];
        *(bf16x8*)&VTlds[sr][sc + 8] = *(const bf16x8*)&Vbase[sr * 1024 + sc + 8];
        if (t < 192) {
            int xr = t / 3, c = t - xr * 3;
            const bf16* xsrc = &xb[((size_t)(b << 10) + j0 + xr) * 48 + c * 16];
            *(bf16x8*)&Xlds[xr][c * 32]     = *(const bf16x8*)&xsrc[0];
            *(bf16x8*)&Xlds[xr][c * 32 + 8] = *(const bf16x8*)&xsrc[8];
            uint2 bp;
            bp.x = ONE2;
            bp.y = spack[((size_t)(b << 10) + j0 + xr) * 3 + c];
            *(uint2*)&Xlds[xr][c * 32 + 16] = bp;
        }
        __syncthreads();

        for (int tt = 0; tt < 4; tt++) {
            f32x4 acc = {};
            bf16x8 kb0 = *(const bf16x8*)&Klds[16 * tt + lo][8 * g];
            bf16x8 kb1 = *(const bf16x8*)&Klds[16 * tt + lo][32 + 8 * g];
            acc = mfma16(qa[0], kb0, acc);
            acc = mfma16(qa[1], kb1, acc);
            f32x4 z0 = {}, z1 = {}, z2 = {};
            f32x4 e0 = mfma16(xqa[0], *(const bf16x8*)&Xlds[16 * tt + lo][8 * g], z0);
            f32x4 e1 = mfma16(xqa[1], *(const bf16x8*)&Xlds[16 * tt + lo][32 + 8 * g], z1);
            f32x4 e2 = mfma16(xqa[2], *(const bf16x8*)&Xlds[16 * tt + lo][64 + 8 * g], z2);
            for (int r = 0; r < 4; r++) {
                float t0 = alf[0] * exp2f(k2[0] * fminf(e0[r], 0.0f));
                t0 = fmaf(alf[1], exp2f(k2[1] * fminf(e1[r], 0.0f)), t0);
                t0 = fmaf(alf[2], exp2f(k2[2] * fminf(e2[r], 0.0f)), t0);
                float p = exp2f(fmaf(acc[r], c1, t0));
                Plds[w][4 * g + r][16 * tt + lo] = (bf16)p;
            }
        }

        bf16x8 pa0 = *(const bf16x8*)&Plds[w][lo][8 * g];
        bf16x8 pa1 = *(const bf16x8*)&Plds[w][lo][32 + 8 * g];
        lacc = mfma16(pa0, ones, lacc);
        lacc = mfma16(pa1, ones, lacc);
        for (int td = 0; td < 4; td++) {
            bf16x8 vb0 = *(const bf16x8*)&VTlds[16 * td + lo][8 * g];
            bf16x8 vb1 = *(const bf16x8*)&VTlds[16 * td + lo][32 + 8 * g];
            o[td] = mfma16(pa0, vb0, o[td]);
            o[td] = mfma16(pa1, vb1, o[td]);
        }
    }

    float inv[4];
    for (int r = 0; r < 4; r++) inv[r] = 1.0f / lacc[r];
    for (int td = 0; td < 4; td++)
        for (int r = 0; r < 4; r++) {
            int i = i0 + 4 * g + r;
            attnout[((size_t)(b << 10) + i) * 512 + hh * 64 + 16 * td + lo] =
                (bf16)(o[td][r] * inv[r]);
        }
}

// ----------------------------------------------------- output GEMM ----------
// 64x128 tile (grid 64x4 = 256 blocks, full chip), BK=64, K=512.
__global__ __launch_bounds__(256) void gemm_out_kernel(
        const bf16* __restrict__ A, const bf16* __restrict__ Bm,
        const float* __restrict__ bias, float* __restrict__ out) {
    __shared__ bf16 Asm[64][72];
    __shared__ bf16 Bsm[128][72];
    int t = threadIdx.x, w = t >> 6, lane = t & 63, g = lane >> 4, lo = lane & 15;
    int rowbase = blockIdx.x * 64, colbase = blockIdx.y * 128;
    int wr = (w >> 1) * 32, wc = (w & 1) * 64;
    f32x4 acc[2][4] = {};
    int arow = t >> 2, acol = (t & 3) * 16;
    int brow = t >> 1, bcol = (t & 1) * 32;
    for (int kb = 0; kb < 512; kb += 64) {
        __syncthreads();
        *(bf16x8*)&Asm[arow][acol]     = *(const bf16x8*)&A[(size_t)(rowbase + arow) * 512 + kb + acol];
        *(bf16x8*)&Asm[arow][acol + 8] = *(const bf16x8*)&A[(size_t)(rowbase + arow) * 512 + kb + acol + 8];
        *(bf16x8*)&Bsm[brow][bcol]      = *(const bf16x8*)&Bm[(size_t)(colbase + brow) * 512 + kb + bcol];
        *(bf16x8*)&Bsm[brow][bcol + 8]  = *(const bf16x8*)&Bm[(size_t)(colbase + brow) * 512 + kb + bcol + 8];
        *(bf16x8*)&Bsm[brow][bcol + 16] = *(const bf16x8*)&Bm[(size_t)(colbase + brow) * 512 + kb + bcol + 16];
        *(bf16x8*)&Bsm[brow][bcol + 24] = *(const bf16x8*)&Bm[(size_t)(colbase + brow) * 512 + kb + bcol + 24];
        __syncthreads();
        for (int kk = 0; kk < 64; kk += 32) {
            bf16x8 af[2], bfr[4];
            for (int m = 0; m < 2; m++) af[m]  = *(const bf16x8*)&Asm[wr + 16 * m + lo][kk + 8 * g];
            for (int n = 0; n < 4; n++) bfr[n] = *(const bf16x8*)&Bsm[wc + 16 * n + lo][kk + 8 * g];
            for (int m = 0; m < 2; m++)
                for (int n = 0; n < 4; n++)
                    acc[m][n] = mfma16(af[m], bfr[n], acc[m][n]);
        }
    }
    for (int n = 0; n < 4; n++) {
        int mcol = colbase + wc + 16 * n + lo;
        float bv = bias[mcol];
        for (int m = 0; m < 2; m++)
            for (int r = 0; r < 4; r++)
                out[(size_t)(rowbase + wr + 16 * m + 4 * g + r) * 512 + mcol] =
                    acc[m][n][r] + bv;
    }
}

// ---------------------------------------------------------------- launch ----
extern "C" void kernel_launch(void* const* d_in, const int* in_sizes, int n_in,
                              void* d_out, int out_size, void* d_ws, size_t ws_size,
                              hipStream_t stream) {
    const float* h  = (const float*)d_in[0];
    const float* x  = (const float*)d_in[1];
    const float* Wq = (const float*)d_in[2];
    const float* bq = (const float*)d_in[3];
    const float* Wk = (const float*)d_in[4];
    const float* bk = (const float*)d_in[5];
    const float* Wv = (const float*)d_in[6];
    const float* bv = (const float*)d_in[7];
    const float* Wo = (const float*)d_in[8];
    const float* bo = (const float*)d_in[9];
    const float* alpha     = (const float*)d_in[10];
    const float* log_sigma = (const float*)d_in[11];
    float* out = (float*)d_out;

    char* ws = (char*)d_ws;
    size_t off = 0;
    auto alloc = [&](size_t bytes) {
        char* p = ws + off;
        off += (bytes + 255) & ~(size_t)255;
        return p;
    };
    bf16*     hb      = (bf16*)alloc(4096 * 512 * 2);
    bf16*     wpack   = (bf16*)alloc(1536 * 512 * 2);
    bf16*     wob     = (bf16*)alloc(512 * 512 * 2);
    float*    bqkv    = (float*)alloc(1536 * 4);
    bf16*     xb      = (bf16*)alloc(4096 * 48 * 2);
    unsigned* spack   = (unsigned*)alloc((size_t)4096 * 3 * 4);
    bf16*     Qb      = (bf16*)alloc((size_t)4 * 8 * 1024 * 64 * 2);
    bf16*     Kb      = (bf16*)alloc((size_t)4 * 8 * 1024 * 64 * 2);
    bf16*     Vt      = (bf16*)alloc((size_t)4 * 8 * 1024 * 64 * 2);
    bf16*     attnout = (bf16*)alloc(4096 * 512 * 2);

    prep_kernel<<<512, 256, 0, stream>>>(h, x, Wq, Wk, Wv, Wo, bq, bk, bv,
                                         hb, wpack, wob, bqkv, xb, spack);
    gemm_qkv_kernel<<<dim3(32, 12), 256, 0, stream>>>(hb, wpack, bqkv, Qb, Kb, Vt);
    attn_kernel<<<dim3(16, 8, 4), 256, 0, stream>>>(
        Qb, Kb, Vt, xb, spack, alpha, log_sigma, attnout);
    gemm_out_kernel<<<dim3(64, 4), 256, 0, stream>>>(attnout, wob, bo, out);
}